// Round 1
// baseline (9313.854 us; speedup 1.0000x reference)
//
#include <hip/hip_runtime.h>
#include <cstddef>
#include <cstdint>

namespace {

constexpr int H  = 512;
constexpr int V  = 32000;
constexpr int B  = 64;
constexpr int S  = 64;
constexpr int T  = 32;
constexpr int TQ = 32;

// ---------------------------------------------------------------------------
// Embedding + positional encoding:
// facts_in[b,s,h] = pe[s,h] * sum_t emb0[ctx[b,s,t], h],  emb0 row0 = 0
// pe[s,h] = 1 - s/S - (h/H)*(1-2s/S)   (exact in f32: all dyadic products)
// ---------------------------------------------------------------------------
__global__ __launch_bounds__(256) void k_embed_facts(const int* __restrict__ ctx,
                                                     const float* __restrict__ emb,
                                                     float* __restrict__ facts_in) {
  const int bs = blockIdx.x;       // b*S + s
  const int s  = bs & (S - 1);
  const int t  = threadIdx.x;
  __shared__ int sidx[T];
  if (t < T) sidx[t] = ctx[(size_t)bs * T + t];
  __syncthreads();
  float a0 = 0.f, a1 = 0.f;
  for (int tt = 0; tt < T; ++tt) {
    const int ix = sidx[tt];
    if (ix != 0) {
      const float* e = emb + ((size_t)ix << 9);
      a0 += e[t];
      a1 += e[t + 256];
    }
  }
  const float sf = (float)s * (1.f / 64.f);
  const float c1 = 1.f - sf;
  const float c2 = (1.f - 2.f * sf) * (1.f / 512.f);
  facts_in[((size_t)bs << 9) + t]       = a0 * (c1 - (float)t * c2);
  facts_in[((size_t)bs << 9) + t + 256] = a1 * (c1 - (float)(t + 256) * c2);
}

__global__ __launch_bounds__(256) void k_embed_q(const int* __restrict__ qidx,
                                                 const float* __restrict__ emb,
                                                 float* __restrict__ qe) {
  const int bt = blockIdx.x;       // b*TQ + t
  const int t  = threadIdx.x;
  const int ix = qidx[bt];
  float v0 = 0.f, v1 = 0.f;
  if (ix != 0) {
    const float* e = emb + ((size_t)ix << 9);
    v0 = e[t];
    v1 = e[t + 256];
  }
  qe[((size_t)bt << 9) + t]       = v0;
  qe[((size_t)bt << 9) + t + 256] = v1;
}

// ---------------------------------------------------------------------------
// 512x512 transpose (for Wr, Ur, W, U which are applied as x @ M, not x @ M.T)
// ---------------------------------------------------------------------------
__global__ __launch_bounds__(256) void k_transpose512(const float* __restrict__ src,
                                                      float* __restrict__ dst) {
  __shared__ float tile[32][33];
  const int x0 = blockIdx.x * 32, y0 = blockIdx.y * 32;
  for (int i = threadIdx.y; i < 32; i += 8)
    tile[i][threadIdx.x] = src[(size_t)(y0 + i) * H + x0 + threadIdx.x];
  __syncthreads();
  for (int i = threadIdx.y; i < 32; i += 8)
    dst[(size_t)(x0 + i) * H + y0 + threadIdx.x] = tile[threadIdx.x][i];
}

// ---------------------------------------------------------------------------
// Generic f32 GEMM (NT): C[M,N] = act(A[M,K] @ B[N,K]^T + bias)
// 64x64 tile, BK=32, 256 threads, 4x4 per thread. M%64==0, N%64==0, K%32==0.
// ACT: 0 none, 1 tanh, 2 relu
// ---------------------------------------------------------------------------
template <int ACT>
__global__ __launch_bounds__(256) void k_gemm_nt(const float* __restrict__ A,
                                                 const float* __restrict__ Bm,
                                                 const float* __restrict__ bias,
                                                 float* __restrict__ C,
                                                 int M, int N, int K) {
  __shared__ __align__(16) float As[32][68];
  __shared__ __align__(16) float Bs[32][68];
  const int t  = threadIdx.x;
  const int tx = t & 15, ty = t >> 4;
  const int m0 = blockIdx.y << 6, n0 = blockIdx.x << 6;
  const int lrow = t >> 3;            // 0..31
  const int lcol = (t & 7) << 2;      // 0,4,...,28
  float acc[4][4] = {};
  for (int k0 = 0; k0 < K; k0 += 32) {
    const float4 a0 = *(const float4*)(A  + (size_t)(m0 + lrow) * K      + k0 + lcol);
    const float4 a1 = *(const float4*)(A  + (size_t)(m0 + lrow + 32) * K + k0 + lcol);
    const float4 b0 = *(const float4*)(Bm + (size_t)(n0 + lrow) * K      + k0 + lcol);
    const float4 b1 = *(const float4*)(Bm + (size_t)(n0 + lrow + 32) * K + k0 + lcol);
    __syncthreads();
    As[lcol + 0][lrow] = a0.x; As[lcol + 1][lrow] = a0.y; As[lcol + 2][lrow] = a0.z; As[lcol + 3][lrow] = a0.w;
    As[lcol + 0][lrow + 32] = a1.x; As[lcol + 1][lrow + 32] = a1.y; As[lcol + 2][lrow + 32] = a1.z; As[lcol + 3][lrow + 32] = a1.w;
    Bs[lcol + 0][lrow] = b0.x; Bs[lcol + 1][lrow] = b0.y; Bs[lcol + 2][lrow] = b0.z; Bs[lcol + 3][lrow] = b0.w;
    Bs[lcol + 0][lrow + 32] = b1.x; Bs[lcol + 1][lrow + 32] = b1.y; Bs[lcol + 2][lrow + 32] = b1.z; Bs[lcol + 3][lrow + 32] = b1.w;
    __syncthreads();
#pragma unroll 4
    for (int kk = 0; kk < 32; ++kk) {
      float a[4], b[4];
      *(float4*)a = *(const float4*)&As[kk][ty << 2];
      *(float4*)b = *(const float4*)&Bs[kk][tx << 2];
#pragma unroll
      for (int i = 0; i < 4; ++i)
#pragma unroll
        for (int j = 0; j < 4; ++j) acc[i][j] += a[i] * b[j];
    }
  }
#pragma unroll
  for (int i = 0; i < 4; ++i) {
    const int m = m0 + (ty << 2) + i;
#pragma unroll
    for (int j = 0; j < 4; ++j) {
      const int n = n0 + (tx << 2) + j;
      float v = acc[i][j];
      if (bias) v += bias[n];
      if (ACT == 1) v = tanhf(v);
      if (ACT == 2) v = fmaxf(v, 0.f);
      C[(size_t)m * N + n] = v;
    }
  }
}

// ---------------------------------------------------------------------------
// One GRU time-step for all three GRUs (fwd ctx, bwd ctx, question).
// grid = 192 WGs: gru = bx>>6; ib = (bx>>4)&3 (16 items); jb = bx&15 (32 cols).
// Weight rows are read with 16-lane same-address broadcast (coalesced by TA).
// ---------------------------------------------------------------------------
__global__ __launch_bounds__(256) void k_gru_step(
    const float* __restrict__ Whh_f, const float* __restrict__ bhh_f,
    const float* __restrict__ Whh_b, const float* __restrict__ bhh_b,
    const float* __restrict__ qWhh,  const float* __restrict__ qbhh,
    const float* __restrict__ gx_f, const float* __restrict__ gx_b,
    const float* __restrict__ gx_q,
    const float* __restrict__ Hf_prev, float* __restrict__ Hf_next,
    const float* __restrict__ Hb_prev, float* __restrict__ Hb_next,
    const float* __restrict__ Hq_prev, float* __restrict__ Hq_next,
    float* __restrict__ facts, float* __restrict__ hb_all, int s) {
  const int bx  = blockIdx.x;
  const int gru = bx >> 6;
  const int ib  = (bx >> 4) & 3;
  const int jb  = bx & 15;
  if (gru == 2 && s >= TQ) return;

  const float* Whh; const float* bhh; const float* gx; const float* Hp; float* Hn;
  int xidx, seqlen;
  if (gru == 0)      { Whh = Whh_f; bhh = bhh_f; gx = gx_f; Hp = Hf_prev; Hn = Hf_next; xidx = s;         seqlen = S;  }
  else if (gru == 1) { Whh = Whh_b; bhh = bhh_b; gx = gx_b; Hp = Hb_prev; Hn = Hb_next; xidx = S - 1 - s; seqlen = S;  }
  else               { Whh = qWhh;  bhh = qbhh;  gx = gx_q; Hp = Hq_prev; Hn = Hq_next; xidx = s;         seqlen = TQ; }

  __shared__ __align__(16) float hs[16][516];   // 16 items x 512 (pad->2-way banks)
  __shared__ float gd[96][17];                  // 96 gate rows x 16 items

  const int t = threadIdx.x;
  if (s == 0) {
    for (int i = t; i < 16 * 512; i += 256) hs[i >> 9][i & 511] = 0.f;
  } else {
    for (int i = t; i < 16 * 128; i += 256) {
      const int item = i >> 7, c4 = (i & 127) << 2;
      *(float4*)&hs[item][c4] = *(const float4*)(Hp + ((size_t)(ib * 16 + item) << 9) + c4);
    }
  }
  __syncthreads();

  // phase 1: gate dots. thread = (item = t&15, rw = t>>4); rows rw+16*rr, rr<6.
  {
    const int item = t & 15;
    const int rw   = t >> 4;
    const float4* wp[6];
#pragma unroll
    for (int rr = 0; rr < 6; ++rr) {
      const int row_local = rw + (rr << 4);          // 0..95
      const int gate = row_local >> 5;               // 0..2
      const int wrow = (gate << 9) + (jb << 5) + (row_local & 31);
      wp[rr] = (const float4*)(Whh + ((size_t)wrow << 9));
    }
    float acc[6] = {};
#pragma unroll 2
    for (int k4 = 0; k4 < 128; ++k4) {
      const float4 h4 = *(const float4*)&hs[item][k4 << 2];
#pragma unroll
      for (int rr = 0; rr < 6; ++rr) {
        const float4 w4 = wp[rr][k4];
        acc[rr] += w4.x * h4.x + w4.y * h4.y + w4.z * h4.z + w4.w * h4.w;
      }
    }
#pragma unroll
    for (int rr = 0; rr < 6; ++rr) gd[rw + (rr << 4)][item] = acc[rr];
  }
  __syncthreads();

  // phase 2: gate nonlinearities + state update (512 outputs, 2 per thread)
  for (int p = t; p < 512; p += 256) {
    const int it2 = p >> 5;            // 0..15
    const int cl  = p & 31;            // 0..31
    const int col = (jb << 5) + cl;
    const int b   = (ib << 4) + it2;
    const size_t gxrow = ((size_t)b * seqlen + xidx) * 1536;
    const float xr = gx[gxrow + col];
    const float xz = gx[gxrow + 512 + col];
    const float xn = gx[gxrow + 1024 + col];
    const float hr = gd[cl][it2]      + bhh[col];
    const float hz = gd[32 + cl][it2] + bhh[512 + col];
    const float hn = gd[64 + cl][it2] + bhh[1024 + col];
    const float hp = hs[it2][col];
    const float r = 1.f / (1.f + expf(-(xr + hr)));
    const float z = 1.f / (1.f + expf(-(xz + hz)));
    const float n = tanhf(xn + r * hn);
    const float hnew = (1.f - z) * n + z * hp;
    Hn[((size_t)b << 9) + col] = hnew;
    if (gru == 0)      facts[((size_t)(b * S + s) << 9) + col]    = hnew;
    else if (gru == 1) hb_all[((size_t)(b * S + xidx) << 9) + col] = hnew;
  }
}

// facts += hb_all (elementwise, float4)
__global__ __launch_bounds__(256) void k_add(float* __restrict__ a, const float* __restrict__ b) {
  const size_t i = (((size_t)blockIdx.x << 8) + threadIdx.x) << 2;
  float4 x = *(float4*)(a + i);
  const float4 y = *(const float4*)(b + i);
  x.x += y.x; x.y += y.y; x.z += y.z; x.w += y.w;
  *(float4*)(a + i) = x;
}

// z[bs, :] = [facts*q, facts*M, |facts-q|, |facts-M|]  (4096 x 2048)
__global__ __launch_bounds__(256) void k_build_z(const float* __restrict__ facts,
                                                 const float* __restrict__ q,
                                                 const float* __restrict__ M,
                                                 float* __restrict__ z) {
  const int bs = blockIdx.x;
  const int b  = bs >> 6;
  const int t  = threadIdx.x;
  const size_t zb = (size_t)bs << 11;
  for (int c = t; c < 512; c += 256) {
    const float f  = facts[((size_t)bs << 9) + c];
    const float qv = q[(b << 9) + c];
    const float mv = M[(b << 9) + c];
    z[zb + c]        = f * qv;
    z[zb + 512 + c]  = f * mv;
    z[zb + 1024 + c] = fabsf(f - qv);
    z[zb + 1536 + c] = fabsf(f - mv);
  }
}

// scores[b,s] = g1[b,s,:] . z2_w + z2_b ; G[b,:] = softmax_s(scores)
__global__ __launch_bounds__(256) void k_score_softmax(const float* __restrict__ g1,
                                                       const float* __restrict__ z2w,
                                                       const float* __restrict__ z2b,
                                                       float* __restrict__ G) {
  const int b = blockIdx.x, t = threadIdx.x;
  const int wave = t >> 6, lane = t & 63;
  __shared__ float sc[64];
  for (int si = 0; si < 16; ++si) {
    const int s = wave * 16 + si;
    const float* row = g1 + ((size_t)(b * S + s) << 9) + lane * 8;
    const float* w   = z2w + lane * 8;
    float p = 0.f;
#pragma unroll
    for (int k = 0; k < 8; ++k) p += row[k] * w[k];
#pragma unroll
    for (int off = 32; off; off >>= 1) p += __shfl_xor(p, off);
    if (lane == 0) sc[s] = p + z2b[0];
  }
  __syncthreads();
  if (wave == 0) {
    const float v = sc[lane];
    float m = v;
#pragma unroll
    for (int off = 32; off; off >>= 1) m = fmaxf(m, __shfl_xor(m, off));
    const float e = expf(v - m);
    float su = e;
#pragma unroll
    for (int off = 32; off; off >>= 1) su += __shfl_xor(su, off);
    G[(b << 6) + lane] = e / su;
  }
}

// One attention-GRU step. grid 128: ib = bx>>5 (16 items), jb = bx&31 (16 cols).
__global__ __launch_bounds__(256) void k_agru_step(
    const float* __restrict__ UrT, const float* __restrict__ UT,
    const float* __restrict__ fRW, const float* __restrict__ fW,
    const float* __restrict__ br, const float* __restrict__ G,
    const float* __restrict__ Cprev, float* __restrict__ Cnext, int s) {
  const int ib = blockIdx.x >> 5;
  const int jb = blockIdx.x & 31;
  const int t  = threadIdx.x;
  __shared__ __align__(16) float cs[16][516];
  if (s == 0) {
    for (int i = t; i < 16 * 512; i += 256) cs[i >> 9][i & 511] = 0.f;
  } else {
    for (int i = t; i < 16 * 128; i += 256) {
      const int item = i >> 7, c4 = (i & 127) << 2;
      *(float4*)&cs[item][c4] = *(const float4*)(Cprev + ((size_t)(ib * 16 + item) << 9) + c4);
    }
  }
  __syncthreads();
  const int item = t >> 4;           // 0..15
  const int cl   = t & 15;           // 0..15
  const int col  = (jb << 4) + cl;
  const int b    = (ib << 4) + item;
  const float4* w0 = (const float4*)(UrT + ((size_t)col << 9));
  const float4* w1 = (const float4*)(UT  + ((size_t)col << 9));
  float acc0 = 0.f, acc1 = 0.f;
#pragma unroll 4
  for (int k4 = 0; k4 < 128; ++k4) {
    const float4 c4v = *(const float4*)&cs[item][k4 << 2];
    const float4 a = w0[k4];
    const float4 d = w1[k4];
    acc0 += a.x * c4v.x + a.y * c4v.y + a.z * c4v.z + a.w * c4v.w;
    acc1 += d.x * c4v.x + d.y * c4v.y + d.z * c4v.z + d.w * c4v.w;
  }
  const float g   = G[(b << 6) + s];
  const size_t fi = ((size_t)(b * S + s) << 9) + col;
  const float brv = br[col];
  const float r  = 1.f / (1.f + expf(-(fRW[fi] + acc0 + brv)));
  const float ht = tanhf(fW[fi] + r * acc1 + brv);
  const float cp = cs[item][col];
  Cnext[((size_t)b << 9) + col] = g * ht + (1.f - g) * cp;
}

// out[b,:] = [M(512), C(512), q(512)]
__global__ __launch_bounds__(256) void k_concat3(const float* __restrict__ M,
                                                 const float* __restrict__ C,
                                                 const float* __restrict__ q,
                                                 float* __restrict__ out) {
  const int b = blockIdx.x, t = threadIdx.x;
  for (int c = t; c < 512; c += 256) {
    out[(size_t)b * 1536 + c]        = M[(b << 9) + c];
    out[(size_t)b * 1536 + 512 + c]  = C[(b << 9) + c];
    out[(size_t)b * 1536 + 1024 + c] = q[(b << 9) + c];
  }
}

// out[b,:] = [M(512), q(512)]
__global__ __launch_bounds__(256) void k_concat2(const float* __restrict__ M,
                                                 const float* __restrict__ q,
                                                 float* __restrict__ out) {
  const int b = blockIdx.x, t = threadIdx.x;
  for (int c = t; c < 512; c += 256) {
    out[(size_t)b * 1024 + c]       = M[(b << 9) + c];
    out[(size_t)b * 1024 + 512 + c] = q[(b << 9) + c];
  }
}

}  // namespace

extern "C" void kernel_launch(void* const* d_in, const int* in_sizes, int n_in,
                              void* d_out, int out_size, void* d_ws, size_t ws_size,
                              hipStream_t stream) {
  const int*   contexts  = (const int*)d_in[0];
  const int*   questions = (const int*)d_in[1];
  const float* emb   = (const float*)d_in[2];
  const float* Wih_f = (const float*)d_in[3];
  const float* Whh_f = (const float*)d_in[4];
  const float* bih_f = (const float*)d_in[5];
  const float* bhh_f = (const float*)d_in[6];
  const float* Wih_b = (const float*)d_in[7];
  const float* Whh_b = (const float*)d_in[8];
  const float* bih_b = (const float*)d_in[9];
  const float* bhh_b = (const float*)d_in[10];
  const float* qWih  = (const float*)d_in[11];
  const float* qWhh  = (const float*)d_in[12];
  const float* qbih  = (const float*)d_in[13];
  const float* qbhh  = (const float*)d_in[14];
  const float* Wr    = (const float*)d_in[15];
  const float* Ur    = (const float*)d_in[16];
  const float* br    = (const float*)d_in[17];
  const float* Wm    = (const float*)d_in[18];
  const float* Um    = (const float*)d_in[19];
  const float* z1_w  = (const float*)d_in[20];
  const float* z1_b  = (const float*)d_in[21];
  const float* z2_w  = (const float*)d_in[22];
  const float* z2_b  = (const float*)d_in[23];
  const float* nm_w  = (const float*)d_in[24];
  const float* nm_b  = (const float*)d_in[25];
  const float* ans_w = (const float*)d_in[26];
  const float* ans_b = (const float*)d_in[27];
  (void)in_sizes; (void)n_in; (void)out_size; (void)ws_size;

  float* ws = (float*)d_ws;
  // ---- workspace layout (floats); total 24,612,864 floats = 98.5 MB ----
  float* WrT      = ws + 0;          // 262144
  float* UrT      = ws + 262144;     // 262144
  float* WT       = ws + 524288;     // 262144
  float* UT       = ws + 786432;     // 262144
  float* facts_in = ws + 1048576;    // 2097152  (reused as fRW after gx GEMMs)
  float* qe       = ws + 3145728;    // 1048576
  float* gx_f     = ws + 4194304;    // 6291456  (reused as z in hops)
  float* gx_b     = ws + 10485760;   // 6291456
  float* gx_q     = ws + 16777216;   // 3145728  (reused as g1 in hops)
  float* facts    = ws + 19922944;   // 2097152
  float* hb       = ws + 22020096;   // 2097152  (reused as fW after k_add)
  float* Hbuf     = ws + 24117248;   // 196608 (6 x 64x512)
  float* C0       = ws + 24313856;   // 32768
  float* C1       = ws + 24346624;   // 32768
  float* M0       = ws + 24379392;   // 32768
  float* M1       = ws + 24412160;   // 32768
  float* MCq      = ws + 24444928;   // 98304
  float* Mq       = ws + 24543232;   // 65536
  float* Gm       = ws + 24608768;   // 4096
  float* zb  = gx_f;      // 8388608 floats, fits in gx_f+gx_b (dead after GRUs)
  float* g1  = gx_q;      // 2097152, gx_q dead after GRUs
  float* fRW = facts_in;  // facts_in dead after gx GEMMs
  float* fW  = hb;        // hb dead after k_add
  float* preds = (float*)d_out;

  float* Hf[2] = {Hbuf,           Hbuf + 32768};
  float* Hb2[2] = {Hbuf + 65536,  Hbuf + 98304};
  float* Hq[2] = {Hbuf + 131072,  Hbuf + 163840};
  float* q = Hq[0];  // final question-GRU state lands here (32 steps, even)
  float* Cb[2] = {C0, C1};

  // ---- stage A: embeddings ----
  k_embed_facts<<<B * S, 256, 0, stream>>>(contexts, emb, facts_in);
  k_embed_q<<<B * TQ, 256, 0, stream>>>(questions, emb, qe);
  dim3 tb(32, 8);
  k_transpose512<<<dim3(16, 16), tb, 0, stream>>>(Wr, WrT);
  k_transpose512<<<dim3(16, 16), tb, 0, stream>>>(Ur, UrT);
  k_transpose512<<<dim3(16, 16), tb, 0, stream>>>(Wm, WT);
  k_transpose512<<<dim3(16, 16), tb, 0, stream>>>(Um, UT);

  // ---- stage B: input-side GRU gate GEMMs ----
  k_gemm_nt<0><<<dim3(24, 64), 256, 0, stream>>>(facts_in, Wih_f, bih_f, gx_f, 4096, 1536, 512);
  k_gemm_nt<0><<<dim3(24, 64), 256, 0, stream>>>(facts_in, Wih_b, bih_b, gx_b, 4096, 1536, 512);
  k_gemm_nt<0><<<dim3(24, 32), 256, 0, stream>>>(qe, qWih, qbih, gx_q, 2048, 1536, 512);

  // ---- stage C: recurrent GRU steps (fwd + bwd + question fused) ----
  for (int s = 0; s < S; ++s) {
    k_gru_step<<<192, 256, 0, stream>>>(Whh_f, bhh_f, Whh_b, bhh_b, qWhh, qbhh,
                                        gx_f, gx_b, gx_q,
                                        Hf[s & 1], Hf[(s + 1) & 1],
                                        Hb2[s & 1], Hb2[(s + 1) & 1],
                                        Hq[s & 1], Hq[(s + 1) & 1],
                                        facts, hb, s);
  }
  k_add<<<2048, 256, 0, stream>>>(facts, hb);  // facts = hf + hb

  // ---- stage D: hop-invariant precomputes ----
  k_gemm_nt<0><<<dim3(8, 64), 256, 0, stream>>>(facts, WrT, nullptr, fRW, 4096, 512, 512);
  k_gemm_nt<0><<<dim3(8, 64), 256, 0, stream>>>(facts, WT,  nullptr, fW,  4096, 512, 512);

  // ---- stage E: episodic memory hops ----
  const float* Mcur = q;
  for (int h = 0; h < 3; ++h) {
    k_build_z<<<B * S, 256, 0, stream>>>(facts, q, Mcur, zb);
    k_gemm_nt<1><<<dim3(8, 64), 256, 0, stream>>>(zb, z1_w, z1_b, g1, 4096, 512, 2048);
    k_score_softmax<<<B, 256, 0, stream>>>(g1, z2_w, z2_b, Gm);
    for (int s = 0; s < S; ++s)
      k_agru_step<<<128, 256, 0, stream>>>(UrT, UT, fRW, fW, br, Gm,
                                           Cb[s & 1], Cb[(s + 1) & 1], s);
    k_concat3<<<B, 256, 0, stream>>>(Mcur, C0, q, MCq);
    float* Mnext = (h & 1) ? M1 : M0;
    k_gemm_nt<2><<<dim3(8, 1), 256, 0, stream>>>(MCq, nm_w, nm_b, Mnext, 64, 512, 1536);
    Mcur = Mnext;
  }

  // ---- stage F: answer projection ----
  k_concat2<<<B, 256, 0, stream>>>(Mcur, q, Mq);
  k_gemm_nt<0><<<dim3(500, 1), 256, 0, stream>>>(Mq, ans_w, ans_b, preds, 64, 32000, 1024);
}